// Round 26
// baseline (696.494 us; speedup 1.0000x reference)
//
#include <hip/hip_runtime.h>
#include <hip/hip_bf16.h>
#include <stdint.h>

#define DEV static __device__ __forceinline__

typedef float f32x4 __attribute__((ext_vector_type(4)));
typedef short bf16x8 __attribute__((ext_vector_type(8)));
typedef float accf4 __attribute__((ext_vector_type(4)));
typedef unsigned short u16;
typedef unsigned int u32;
typedef unsigned long long u64;
typedef u16 u16x4 __attribute__((ext_vector_type(4)));

#define BB 4
#define TT 1024
#define DD 1024
#define HH 8
#define DKK 128
#define DVV 128
#define MM (BB*TT)
#define DFF 4096
#define SKQ 4096   // qkvd row stride

DEV u16 f2b(float f){
  union { float f; u32 u; } v; v.f = f;
  u32 r = (v.u + 0x7fffu + ((v.u >> 16) & 1u)) >> 16;
  return (u16)r;
}
DEV float b2f(u16 h){
  union { u32 u; float f; } v; v.u = ((u32)h) << 16;
  return v.f;
}
DEV float sigm(float x){ return 1.f / (1.f + __expf(-x)); }
DEV float silu_f(float x){ return x / (1.f + __expf(-x)); }

DEV void gl_lds16(const void* g, void* l){
  __builtin_amdgcn_global_load_lds(
      (const __attribute__((address_space(1))) void*)g,
      (__attribute__((address_space(3))) void*)l, 16, 0, 0);
}

// ---- DPP cross-lane adds ----
template<int CTRL>
DEV float dpp_add(float x){
  union { float f; int i; } u; u.f = x;
  int y = __builtin_amdgcn_update_dpp(0, u.i, CTRL, 0xf, 0xf, true);
  union { int i; float f; } w; w.i = y;
  return x + w.f;
}
DEV float red16(float x){
  x = dpp_add<0xB1>(x);
  x = dpp_add<0x4E>(x);
  x = dpp_add<0x141>(x);
  x = dpp_add<0x140>(x);
  return x;
}
DEV float red64_last(float x){
  x = red16(x);
  x = dpp_add<0x142>(x);
  x = dpp_add<0x143>(x);
  return x;
}

// ---------------- GEMM 128x128 body (shared by gemm_bt + fat kernels) ------
// 2-phase schedule (best-measured for this body; R24's depth-2 regressed).
// OP 0: C=acc(+bias)   OP 1: C+=acc   OP 2: Cb=bf16(silu(acc+bias))
// OP 3: interleaved swiglu epilogue   OP 4: alpha epilogue
template<int OP>
DEV void gemm128_body(
    const u16* __restrict__ A, const u16* __restrict__ Bm,
    float* __restrict__ C, u16* __restrict__ Cb,
    const float* __restrict__ bias,
    const u64* __restrict__ spkp, const float* __restrict__ aspkp,
    int N, int K, int lda, int ldb, int ldc,
    int bm, int bn, char* smem)
{
  u16* lsA0 = (u16*)smem;
  u16* lsA1 = (u16*)(smem + 16384);
  u16* lsB0 = (u16*)(smem + 32768);
  u16* lsB1 = (u16*)(smem + 49152);
  const int tid = threadIdx.x;
  const int wid = tid >> 6, lane = tid & 63;
  const int wr = wid >> 1, wc = wid & 1;
  const int fr = lane & 15, fq = lane >> 4;
  accf4 acc[4][4];
#pragma unroll
  for (int i=0;i<4;i++)
#pragma unroll
    for (int j=0;j<4;j++) acc[i][j] = (accf4)0.f;

  const int srow = tid >> 3;
  const int sk = (tid & 7) * 8;
  const u16* aP = A + (size_t)(bm*128 + srow) * lda + sk;
  const u16* bP = Bm + (size_t)(bn*128 + srow) * ldb + sk;

  auto STAGE = [&](int buf, int t){
    char* lA = (char*)(buf ? lsA1 : lsA0) + tid*16;
    char* lB = (char*)(buf ? lsB1 : lsB0) + tid*16;
    const u16* a = aP + (size_t)t*64;
    const u16* b = bP + (size_t)t*64;
#pragma unroll
    for (int it=0; it<4; ++it) {
      gl_lds16(a + (size_t)it*32*lda, lA + it*4096);
      gl_lds16(b + (size_t)it*32*ldb, lB + it*4096);
    }
  };

  const int nk = K >> 6;
  STAGE(0, 0);
  asm volatile("s_waitcnt vmcnt(0)" ::: "memory");
  __syncthreads();
  int cur = 0;
  for (int t = 0; t < nk; ++t) {
    if (t + 1 < nk) STAGE(cur ^ 1, t + 1);
    const u16* la = cur ? lsA1 : lsA0;
    const u16* lb = cur ? lsB1 : lsB0;
#pragma unroll
    for (int ks=0; ks<2; ++ks) {
      bf16x8 av[4], bv[4];
#pragma unroll
      for (int i=0;i<4;i++)
        av[i] = *(const bf16x8*)&la[(wr*64 + i*16 + fr)*64 + ks*32 + fq*8];
#pragma unroll
      for (int j=0;j<4;j++)
        bv[j] = *(const bf16x8*)&lb[(wc*64 + j*16 + fr)*64 + ks*32 + fq*8];
#pragma unroll
      for (int i=0;i<4;i++)
#pragma unroll
        for (int j=0;j<4;j++)
          acc[i][j] = __builtin_amdgcn_mfma_f32_16x16x32_bf16(av[i], bv[j], acc[i][j], 0, 0, 0);
    }
    asm volatile("s_waitcnt vmcnt(0)" ::: "memory");
    __syncthreads();
    cur ^= 1;
  }

  if constexpr (OP == 3) {
#pragma unroll
    for (int i=0;i<4;i++) {
      const int r0 = bm*128 + wr*64 + i*16 + fq*4;
#pragma unroll
      for (int j=0;j<4;j+=2) {
        const int oc = bn*64 + wc*32 + (j>>1)*16 + fr;
#pragma unroll
        for (int rr=0; rr<4; ++rr) {
          Cb[(size_t)(r0+rr)*ldc + oc] =
              f2b(silu_f(acc[i][j][rr]) * acc[i][j+1][rr]);
        }
      }
    }
  } else if constexpr (OP == 4) {
#pragma unroll
    for (int i=0;i<4;i++) {
      const int r0 = bm*128 + wr*64 + i*16 + fq*4;
#pragma unroll
      for (int j=0;j<4;j++) {
        const int c = bn*128 + wc*64 + j*16 + fr;
        const int hq = c >> 7, dkh = c & 127;
        const float asv = aspkp[c];
        const float bv = bias[c];
#pragma unroll
        for (int rr=0; rr<4; ++rr) {
          const int r = r0 + rr;
          const int bq = r >> 10, tq = r & 1023;
          const u64 mask = spkp[(((size_t)(bq*8 + hq))*TT + tq)*2 + (dkh>>6)];
          const float add = ((mask >> (dkh & 63)) & 1ull) ? asv : 0.f;
          C[(size_t)r*ldc + c] = sigm(acc[i][j][rr] + bv + add);
        }
      }
    }
  } else {
#pragma unroll
    for (int i=0;i<4;i++) {
      const int r0 = bm*128 + wr*64 + i*16 + fq*4;
#pragma unroll
      for (int j=0;j<4;j++) {
        const int c = bn*128 + wc*64 + j*16 + fr;
#pragma unroll
        for (int rr=0; rr<4; ++rr) {
          const size_t idx = (size_t)(r0+rr)*ldc + c;
          float v = acc[i][j][rr];
          if (OP == 0) { if (bias) v += bias[c]; C[idx] = v; }
          if (OP == 1) { C[idx] += v; }
          if (OP == 2) { v += bias[c]; Cb[idx] = f2b(silu_f(v)); }
        }
      }
    }
  }
}

template<int OP>
__global__ __launch_bounds__(256) void gemm_bt(
    const u16* __restrict__ A, const u16* __restrict__ Bm,
    float* __restrict__ C, u16* __restrict__ Cb,
    const float* __restrict__ bias,
    const u64* __restrict__ spkp, const float* __restrict__ aspkp,
    int N, int K, int lda, int ldb, int ldc)
{
  __shared__ __align__(16) char smem[65536];
  gemm128_body<OP>(A, Bm, C, Cb, bias, spkp, aspkp, N, K, lda, ldb, ldc,
                   blockIdx.x, blockIdx.y, smem);
}

// ---------------- GEMM 256x256: ring-4 half-tile counted pipeline (R26) ----
// T3/T4: K split into 32-wide halves; 4 LDS half-slots (32KB each, 128KB
// total — same budget). Phase p: STAGE h(p+2)->slot (p+2)&3 (4 loads/thr);
// vmcnt(8) [outstanding = h(p+1)+h(p+2) = 8 -> drains exactly h(p), NEVER 0
// in main loop]; barrier [h(p) visible everywhere + all waves done with
// compute(p-2), so the slot we just staged into was idle]; 12 ds_read_b128 +
// 32 MFMA on h(p). Loads get ~2 phases (~800cy) of lead time vs 0 in the
// 2-phase schedule. Epilogue peels vmcnt(4)/vmcnt(0). Race-freedom: slot
// (p+2)&3 == (p-2)&3 last read in phase p-2; barrier chain B(p-1) implies
// all waves finished compute(p-2). NH = K/32 >= 32 at both call sites.
// OP 0: C=acc   OP 3: swiglu interleave epilogue (fwcat pairing)
template<int OP>
__global__ __launch_bounds__(512) void gemm256(
    const u16* __restrict__ A, const u16* __restrict__ Bm,
    float* __restrict__ C, u16* __restrict__ Cb,
    int K, int lda, int ldb, int ldc)
{
  __shared__ u16 lsA[4][256*32];   // 4 half-slots x 16KB
  __shared__ u16 lsB[4][256*32];
  const int tid = threadIdx.x;
  const int bm = blockIdx.x, bn = blockIdx.y;
  const int wid = tid >> 6, lane = tid & 63;
  const int wr = wid >> 2, wc = wid & 3;
  const int fr = lane & 15, fq = lane >> 4;
  accf4 acc[8][4];
#pragma unroll
  for (int i=0;i<8;i++)
#pragma unroll
    for (int j=0;j<4;j++) acc[i][j] = (accf4)0.f;

  const int srow = tid >> 2;          // 0..127 (4 threads/row cover 32 cols)
  const int sk = (tid & 3) * 8;
  const u16* aP = A + (size_t)(bm*256 + srow) * lda + sk;
  const u16* bP = Bm + (size_t)(bn*256 + srow) * ldb + sk;

  // stage K-half h (global k-offset h*32) into slot s: 4 gl_lds16/thread
  auto STAGE = [&](int s, int h){
    char* lA = (char*)lsA[s] + tid*16;
    char* lB = (char*)lsB[s] + tid*16;
    const u16* a = aP + (size_t)h*32;
    const u16* b = bP + (size_t)h*32;
#pragma unroll
    for (int it=0; it<2; ++it) {
      gl_lds16(a + (size_t)it*128*lda, lA + it*8192);
      gl_lds16(b + (size_t)it*128*ldb, lB + it*8192);
    }
  };

  // compute one K=32 half from slot s: 12 ds_read_b128 + 32 MFMA
  auto COMPUTE = [&](int s){
    bf16x8 av[8], bv[4];
#pragma unroll
    for (int i=0;i<8;i++)
      av[i] = *(const bf16x8*)&lsA[s][(wr*128 + i*16 + fr)*32 + fq*8];
#pragma unroll
    for (int j=0;j<4;j++)
      bv[j] = *(const bf16x8*)&lsB[s][(wc*64 + j*16 + fr)*32 + fq*8];
#pragma unroll
    for (int i=0;i<8;i++)
#pragma unroll
      for (int j=0;j<4;j++)
        acc[i][j] = __builtin_amdgcn_mfma_f32_16x16x32_bf16(av[i], bv[j], acc[i][j], 0, 0, 0);
  };

  const int NH = K >> 5;              // halves; >= 32 at all call sites
  STAGE(0, 0);
  STAGE(1, 1);
  for (int p = 0; p < NH - 2; ++p) {
    STAGE((p + 2) & 3, p + 2);
    asm volatile("s_waitcnt vmcnt(8)" ::: "memory");
    __syncthreads();
    COMPUTE(p & 3);
  }
  asm volatile("s_waitcnt vmcnt(4)" ::: "memory");
  __syncthreads();
  COMPUTE((NH - 2) & 3);
  asm volatile("s_waitcnt vmcnt(0)" ::: "memory");
  __syncthreads();
  COMPUTE((NH - 1) & 3);

  if constexpr (OP == 3) {
#pragma unroll
    for (int i=0;i<8;i++) {
      const int r0 = bm*256 + wr*128 + i*16 + fq*4;
#pragma unroll
      for (int j=0;j<4;j+=2) {
        const int rb = bn*256 + wc*64 + j*16 + fr;
        const int oc = (rb>>7)*64 + (((rb>>4)&7)>>1)*16 + (rb&15);
#pragma unroll
        for (int rr=0; rr<4; ++rr) {
          Cb[(size_t)(r0+rr)*ldc + oc] =
              f2b(silu_f(acc[i][j][rr]) * acc[i][j+1][rr]);
        }
      }
    }
  } else {
#pragma unroll
    for (int i=0;i<8;i++) {
      const int r0 = bm*256 + wr*128 + i*16 + fq*4;
#pragma unroll
      for (int j=0;j<4;j++) {
        const int c = bn*256 + wc*64 + j*16 + fr;
#pragma unroll
        for (int rr=0; rr<4; ++rr)
          C[(size_t)(r0+rr)*ldc + c] = acc[i][j][rr];
      }
    }
  }
}

// ---------------- fatP: weight/input prep (22145) | row_rms (4096) ---------
__global__ __launch_bounds__(256) void prep_all(
    const float* __restrict__ qw, const float* __restrict__ kw,
    const float* __restrict__ vw, const float* __restrict__ sw,
    const float* __restrict__ ow, const float* __restrict__ fw1,
    const float* __restrict__ fw3, const float* __restrict__ fw2,
    const float* __restrict__ x, const float* __restrict__ aupw,
    const float* __restrict__ adnw, const float* __restrict__ betw,
    const float* __restrict__ u1w, const float* __restrict__ u2w,
    const float* __restrict__ aupb, const float* __restrict__ betb,
    const float* __restrict__ u1b,
    u16* __restrict__ wcat4, u16* __restrict__ swcat, u16* __restrict__ owb,
    u16* __restrict__ fwcat, u16* __restrict__ fw2b, u16* __restrict__ xbf,
    u16* __restrict__ aupwb, u16* __restrict__ adnwb, u16* __restrict__ betwb,
    u16* __restrict__ u1wb, u16* __restrict__ u2wb,
    float* __restrict__ aupbp, float* __restrict__ betbp, float* __restrict__ u1bp,
    float* __restrict__ invr)
{
  const int bid = blockIdx.x, tid = threadIdx.x;
  auto cvt4 = [&](const float* s, u16* d, int base){
    size_t i = ((size_t)(bid - base)*256 + tid)*4;
    f32x4 v = *(const f32x4*)(s + i);
    u16x4 o; o.x=f2b(v.x); o.y=f2b(v.y); o.z=f2b(v.z); o.w=f2b(v.w);
    *(u16x4*)(d + i) = o;
  };
  auto pad4 = [&](const float* s, u16* d, int base, int sr, int sc, int dc){
    size_t i = ((size_t)(bid - base)*256 + tid)*4;
    int r = (int)(i / dc), c = (int)(i % dc);
    u16x4 o;
#pragma unroll
    for (int e=0;e<4;e++){
      float v = (r < sr && c+e < sc) ? s[(size_t)r*sc + c + e] : 0.f;
      o[e] = f2b(v);
    }
    *(u16x4*)(d + i) = o;
  };
  if (bid < 1024)       cvt4(qw, wcat4, 0);
  else if (bid < 2048)  cvt4(kw, wcat4 + (size_t)1024*1024, 1024);
  else if (bid < 3072)  cvt4(vw, wcat4 + (size_t)2*1024*1024, 2048);
  else if (bid < 4096) {
    size_t i = ((size_t)(bid - 3072)*256 + tid)*4;
    int r = (int)(i >> 10), c = (int)(i & 1023);
    f32x4 v = *(const f32x4*)(sw + i);
    u16x4 h, l;
    h.x=f2b(v.x); h.y=f2b(v.y); h.z=f2b(v.z); h.w=f2b(v.w);
    l.x=f2b(v.x-b2f(h.x)); l.y=f2b(v.y-b2f(h.y)); l.z=f2b(v.z-b2f(h.z)); l.w=f2b(v.w-b2f(h.w));
    *(u16x4*)(wcat4 + (size_t)3*1024*1024 + i) = h;
    *(u16x4*)(swcat + (size_t)r*2048 + 1024 + c) = h;
    *(u16x4*)(swcat + (size_t)r*2048 + c) = l;
  }
  else if (bid < 5120)  cvt4(ow, owb, 4096);
  else if (bid < 13312) {
    int r = bid - 5120;                 // [0, 8192)
    int t128 = r >> 7, s8 = (r >> 4) & 7, row16 = r & 15;
    int srow = t128*64 + (s8 >> 1)*16 + row16;
    const float* src = (s8 & 1) ? fw3 : fw1;
    size_t si = (size_t)srow*1024 + tid*4;
    f32x4 v = *(const f32x4*)(src + si);
    u16x4 o; o.x=f2b(v.x); o.y=f2b(v.y); o.z=f2b(v.z); o.w=f2b(v.w);
    *(u16x4*)(fwcat + (size_t)r*1024 + tid*4) = o;
  }
  else if (bid < 17408) cvt4(fw2, fw2b, 13312);
  else if (bid < 21504) cvt4(x, xbf, 17408);
  else if (bid < 21632) pad4(aupw, aupwb, 21504, 64, 1024, 1024);
  else if (bid < 21760) pad4(adnw, adnwb, 21632, 1024, 64, 128);
  else if (bid < 21888) pad4(betw, betwb, 21760, 8, 1024, 1024);
  else if (bid < 22016) pad4(u1w, u1wb, 21888, 64, 1024, 1024);
  else if (bid < 22144) pad4(u2w, u2wb, 22016, 1024, 64, 128);
  else if (bid == 22144) {
    if (tid < 128) {
      aupbp[tid] = tid < 64 ? aupb[tid] : 0.f;
      betbp[tid] = tid < 8  ? betb[tid] : 0.f;
      u1bp[tid]  = tid < 64 ? u1b[tid]  : 0.f;
    }
  }
  else {
    // row_rms for row m = bid - 22145
    int m = bid - 22145;
    f32x4 v = *(const f32x4*)(x + (size_t)m*DD + tid*4);
    float s = v.x*v.x + v.y*v.y + v.z*v.z + v.w*v.w;
#pragma unroll
    for (int msk=1; msk<64; msk<<=1) s += __shfl_xor(s, msk);
    __shared__ float ws[4];
    if ((tid&63)==0) ws[tid>>6] = s;
    __syncthreads();
    if (tid==0) invr[m] = 1.f / sqrtf((ws[0]+ws[1]+ws[2]+ws[3])*(1.f/DD) + 1e-6f);
  }
}

// ---------------- norm + causal conv + silu -> bf16 [hi|lo] cat ------------
__global__ __launch_bounds__(256) void conv_silu_k(
    const float* __restrict__ x, const float* __restrict__ invr,
    const float* __restrict__ nw, const float* __restrict__ cw, const float* __restrict__ cb,
    u16* __restrict__ hcat)
{
  int m = blockIdx.x, tid = threadIdx.x;
  int b = m >> 10, t = m & 1023;
  int d4 = tid * 4;
  f32x4 acc = *(const f32x4*)(cb + d4);
  f32x4 nwv = *(const f32x4*)(nw + d4);
  f32x4 w0 = *(const f32x4*)(cw + (size_t)(d4+0)*4);
  f32x4 w1 = *(const f32x4*)(cw + (size_t)(d4+1)*4);
  f32x4 w2 = *(const f32x4*)(cw + (size_t)(d4+2)*4);
  f32x4 w3 = *(const f32x4*)(cw + (size_t)(d4+3)*4);
#pragma unroll
  for (int j=0;j<4;j++) {
    int tt = t - 3 + j;
    if (tt >= 0) {
      int m2 = (b<<10) + tt;
      f32x4 xv = *(const f32x4*)(x + (size_t)m2*DD + d4);
      float sc = invr[m2];
      acc.x += xv.x * sc * nwv.x * w0[j];
      acc.y += xv.y * sc * nwv.y * w1[j];
      acc.z += xv.z * sc * nwv.z * w2[j];
      acc.w += xv.w * sc * nwv.w * w3[j];
    }
  }
  float h0 = silu_f(acc.x), h1 = silu_f(acc.y), h2 = silu_f(acc.z), h3 = silu_f(acc.w);
  size_t o = (size_t)m*2048 + d4;
  u16x4 hv; hv.x=f2b(h0); hv.y=f2b(h1); hv.z=f2b(h2); hv.w=f2b(h3);
  u16x4 lv; lv.x=f2b(h0-b2f(hv.x)); lv.y=f2b(h1-b2f(hv.y)); lv.z=f2b(h2-b2f(hv.z)); lv.w=f2b(h3-b2f(hv.w));
  *(u16x4*)(hcat + o) = hv;
  *(u16x4*)(hcat + o + 1024) = lv;
}

// ---------------- q/k L2 normalization body (stride 4096) ------------------
DEV void qknorm_body(int gwblk, float* __restrict__ qkv){
  int gw = gwblk*4 + (threadIdx.x>>6);
  int lane = threadIdx.x & 63;
  size_t off = (size_t)(gw>>3)*SKQ + (size_t)(gw&7)*DKK;
  float* q = qkv + off;
  float* k = qkv + off + 1024;
  float q1 = q[lane], q2 = q[lane+64];
  float k1 = k[lane], k2 = k[lane+64];
  float sq = q1*q1+q2*q2, sk = k1*k1+k2*k2;
#pragma unroll
  for (int msk=1; msk<64; msk<<=1){ sq += __shfl_xor(sq,msk); sk += __shfl_xor(sk,msk); }
  float iq = 1.f/(sqrtf(sq)+1e-6f), ik = 1.f/(sqrtf(sk)+1e-6f);
  q[lane]=q1*iq; q[lane+64]=q2*iq;
  k[lane]=k1*ik; k[lane+64]=k2*ik;
}

// ---------------- headwise RMSNorm -> bf16 ---------------------------------
__global__ __launch_bounds__(256) void head_norm_k(
    const float* __restrict__ y, const float* __restrict__ w, u16* __restrict__ o)
{
  int gw = blockIdx.x*4 + (threadIdx.x>>6);
  int lane = threadIdx.x & 63;
  int h = gw & 7;
  size_t off = (size_t)(gw>>3)*DD + (size_t)h*DVV;
  float y1 = y[off+lane], y2 = y[off+lane+64];
  float s = y1*y1 + y2*y2;
#pragma unroll
  for (int msk=1; msk<64; msk<<=1) s += __shfl_xor(s,msk);
  float inv = 1.f / sqrtf(s*(1.f/DVV) + 1e-6f);
  o[off+lane]    = f2b(y1*inv*w[h*DVV+lane]);
  o[off+lane+64] = f2b(y2*inv*w[h*DVV+lane+64]);
}

// ---------------- LIF spike scan body (LDS-DMA double buffer) --------------
DEV void spike_body(
    int bh, char* smem,
    const float* __restrict__ dr, const float* __restrict__ bbase,
    const float* __restrict__ bspk, const float* __restrict__ mem0,
    u64* __restrict__ spk, float* __restrict__ bs)
{
  const int tid = threadIdx.x;
  if (tid >= 64) return;               // one wave does the scan
  float* bufA = (float*)smem;          // 32KB
  float* bufB = (float*)(smem + 32768);// 32KB
  float* bb_lds = (float*)(smem + 65536); // 4KB
  const int b = bh>>3, h = bh&7;
  const int lane = tid;

  for (int i=0;i<16;++i)
    bb_lds[i*64 + lane] = bbase[((size_t)b*TT + i*64 + lane)*128 + h];

  float m1 = mem0[bh*DKK + lane], m2 = mem0[bh*DKK + lane + 64];
  const float b1s = bspk[h*DKK+lane], b2s = bspk[h*DKK+lane+64];

  const char* drBase = (const char*)(dr + ((size_t)b*TT)*SKQ + (size_t)h*DKK);
  const int rowp = lane>>5, col = lane&31;
  asm volatile("s_waitcnt vmcnt(0) lgkmcnt(0)" ::: "memory");

  auto DMA = [&](int c){
    char* l = (char*)((c&1) ? bufB : bufA);
    const char* g = drBase + ((size_t)(c*64 + rowp)*SKQ + (size_t)col*4)*4;
#pragma unroll
    for (int j=0;j<32;++j)
      gl_lds16(g + (size_t)j*2*SKQ*4, l + j*1024);
  };

  auto CHUNK = [&](int c){
    const float* lf = (c&1) ? bufB : bufA;
    u32 q0=0,q1=0,q2=0,q3=0; float qss=0.f;
#pragma unroll 8
    for (int t=0;t<64;++t){
      float d1 = lf[t*128 + lane];
      float d2 = lf[t*128 + 64 + lane];
      m1 = 0.9f*m1 + d1; m2 = 0.9f*m2 + d2;
      bool p1 = m1 > 0.5f, p2 = m2 > 0.5f;
      u64 bl1 = __ballot(p1), bl2 = __ballot(p2);
      float sp1 = p1 ? 1.f : 0.f, sp2 = p2 ? 1.f : 0.f;
      m1 -= sp1*0.5f; m2 -= sp2*0.5f;
      float ss = red64_last(sp1*b1s + sp2*b2s);
      float ssv = __shfl(ss, 63);
      if (lane == t){
        q0=(u32)bl1; q1=(u32)(bl1>>32);
        q2=(u32)bl2; q3=(u32)(bl2>>32);
        qss=ssv;
      }
    }
    const int tg = c*64 + lane;
    float bv = bb_lds[tg];
    bool act = (q0|q1|q2|q3) != 0u;
    float beta = act ? sigm(bv + qss) : 0.f;
    u32* sp32 = (u32*)(spk + ((size_t)bh*TT + tg)*2);
    uint4 m4; m4.x=q0; m4.y=q1; m4.z=q2; m4.w=q3;
    *(uint4*)sp32 = m4;
    bs[((size_t)b*TT + tg)*HH + h] = beta;
  };

  DMA(0); DMA(1);
  for (int c=0; c<16; ++c){
    if (c == 0)       asm volatile("s_waitcnt vmcnt(32)" ::: "memory");
    else if (c < 15)  asm volatile("s_waitcnt vmcnt(34)" ::: "memory");
    else              asm volatile("s_waitcnt vmcnt(2)"  ::: "memory");
    CHUNK(c);
    if (c+2 < 16) DMA(c+2);
  }
}

// ---------------- gated delta-rule scan body (R10/R17/R19 best) ------------
DEV void scan_body(
    int bx,
    const float* __restrict__ qkv, const float* __restrict__ al,
    const float* __restrict__ bs, const float* __restrict__ s0p,
    float* __restrict__ y)
{
  const int bh = bx & 31, dvb = bx >> 5;
  const int b = bh >> 3, h = bh & 7;
  const int tid = threadIdx.x;
  const int dvl = tid >> 4, dkl = tid & 15;
  const int dv = dvb*16 + dvl;
  const int dk0 = dkl*8;

  float s[8];
  {
    const float* sp = s0p + ((size_t)bh*DKK + dk0) * DVV + dv;
#pragma unroll
    for (int i=0;i<8;i++) s[i] = sp[(size_t)i*DVV];
  }
  const size_t rq = ((size_t)b*TT)*SKQ + (size_t)h*DKK;
  const size_t ra = ((size_t)b*TT)*DD + (size_t)h*DKK;
  const float* qP = qkv + rq + dk0;
  const float* kP = qkv + rq + 1024 + dk0;
  const float* vP = qkv + rq + 2048 + dv;
  const float* aP = al + ra + dk0;
  const float* bP = bs + (size_t)b*TT*HH + h;
  float* yP = y + ra + dv;

  struct Buf { f32x4 kk[2], qq[2], aa[2]; float vv, bb; };
  Buf B0,B1,B2,B3,B4,B5,B6,B7;
  auto LOAD = [&](int t_, Buf& Bx){
    size_t o = (size_t)t_*SKQ;
    size_t oa = (size_t)t_*DD;
    Bx.kk[0] = *(const f32x4*)(kP + o); Bx.kk[1] = *(const f32x4*)(kP + o + 4);
    Bx.qq[0] = *(const f32x4*)(qP + o); Bx.qq[1] = *(const f32x4*)(qP + o + 4);
    Bx.aa[0] = *(const f32x4*)(aP + oa); Bx.aa[1] = *(const f32x4*)(aP + oa + 4);
    Bx.vv = vP[o];
    Bx.bb = bP[(size_t)t_*HH];
  };
  auto STEP = [&](const Buf& Bx, int t_){
    float pp = 0.f, pp2 = 0.f;
#pragma unroll
    for (int i=0;i<2;i++)
#pragma unroll
      for (int e=0;e<4;e++){
        float sv = s[i*4+e] * Bx.aa[i][e];
        s[i*4+e] = sv;
        if (e < 2) pp += sv * Bx.kk[i][e]; else pp2 += sv * Bx.kk[i][e];
      }
    pp = red16(pp + pp2);
    float err = Bx.bb * (Bx.vv - pp);
    float oo = 0.f, oo2 = 0.f;
#pragma unroll
    for (int i=0;i<2;i++)
#pragma unroll
      for (int e=0;e<4;e++){
        float sv = s[i*4+e] + Bx.kk[i][e] * err;
        s[i*4+e] = sv;
        if (e < 2) oo += sv * Bx.qq[i][e]; else oo2 += sv * Bx.qq[i][e];
      }
    oo = red16(oo + oo2);
    if (dkl == 0) yP[(size_t)t_*DD] = oo;
  };

#define SBAR __builtin_amdgcn_sched_barrier(0)
  LOAD(0,B0); LOAD(1,B1); LOAD(2,B2); LOAD(3,B3);
  LOAD(4,B4); LOAD(5,B5); LOAD(6,B6);
  SBAR;
  for (int t=0; t<TT; t+=8){
    LOAD(t+ 7 < TT ? t+ 7 : TT-1, B7); SBAR; STEP(B0, t);   SBAR;
    LOAD(t+ 8 < TT ? t+ 8 : TT-1, B0); SBAR; STEP(B1, t+1); SBAR;
    LOAD(t+ 9 < TT ? t+ 9 : TT-1, B1); SBAR; STEP(B2, t+2); SBAR;
    LOAD(t+10 < TT ? t+10 : TT-1, B2); SBAR; STEP(B3, t+3); SBAR;
    LOAD(t+11 < TT ? t+11 : TT-1, B3); SBAR; STEP(B4, t+4); SBAR;
    LOAD(t+12 < TT ? t+12 : TT-1, B4); SBAR; STEP(B5, t+5); SBAR;
    LOAD(t+13 < TT ? t+13 : TT-1, B5); SBAR; STEP(B6, t+6); SBAR;
    LOAD(t+14 < TT ? t+14 : TT-1, B6); SBAR; STEP(B7, t+7); SBAR;
  }
#undef SBAR
}

// ---------------- fatA: spike_scan(32) | aup GEMM(32) | u1 GEMM(32) --------
__global__ __launch_bounds__(256) void fatA(
    const float* __restrict__ dr, const float* __restrict__ bbase,
    const float* __restrict__ bspk, const float* __restrict__ mem0,
    u64* __restrict__ spk, float* __restrict__ bs,
    const u16* __restrict__ hcat, const u16* __restrict__ aupwb,
    u16* __restrict__ gsm, const float* __restrict__ aupbp,
    const u16* __restrict__ xbf, const u16* __restrict__ u1wb,
    u16* __restrict__ g1, const float* __restrict__ u1bp)
{
  __shared__ __align__(16) char smem[69632];
  const int bx = blockIdx.x;
  if (bx < 32) {
    spike_body(bx, smem, dr, bbase, bspk, mem0, spk, bs);
  } else if (bx < 64) {
    gemm128_body<2>(hcat, aupwb, nullptr, gsm, aupbp, nullptr, nullptr,
                    128, DD, 2048, DD, 128, bx - 32, 0, smem);
  } else {
    gemm128_body<2>(xbf, u1wb, nullptr, g1, u1bp, nullptr, nullptr,
                    128, DD, DD, DD, 128, bx - 64, 0, smem);
  }
}

// ---------------- fatC: drive-lo GEMM(256) | beta GEMM(32) | qk_norm(8192) --
// drive-lo accumulates into qkvd cols 3072+ (depends on qkvd gemm); beta and
// qk_norm (cols 0..2047) are disjoint/independent — all safely co-dispatched.
__global__ __launch_bounds__(256) void fatC(
    const u16* __restrict__ hcat, const u16* __restrict__ swcat,
    float* __restrict__ qkvd,
    const u16* __restrict__ betwb, float* __restrict__ bbase,
    const float* __restrict__ betbp)
{
  __shared__ __align__(16) char smem[65536];
  const int bx = blockIdx.x;
  if (bx < 256) {
    gemm128_body<1>(hcat, swcat, qkvd + 3072, nullptr, nullptr, nullptr, nullptr,
                    DD, 2048, 2048, 2048, SKQ, bx & 31, bx >> 5, smem);
  } else if (bx < 288) {
    gemm128_body<0>(hcat, betwb, bbase, nullptr, betbp, nullptr, nullptr,
                    128, DD, 2048, DD, 128, bx - 256, 0, smem);
  } else {
    qknorm_body(bx - 288, qkvd);
  }
}

// ---------------- fatB: scan_k(256) | u2 GEMM(256) -------------------------
__global__ __launch_bounds__(256) void fatB(
    const float* __restrict__ qkv, const float* __restrict__ al,
    const float* __restrict__ bs, const float* __restrict__ s0p,
    float* __restrict__ y,
    const u16* __restrict__ g1, const u16* __restrict__ u2wb,
    float* __restrict__ gpre, const float* __restrict__ u2b)
{
  __shared__ __align__(16) char smem[65536];
  const int bx = blockIdx.x;
  if (bx < 256) {
    scan_body(bx, qkv, al, bs, s0p, y);
  } else {
    const int idx = bx - 256;
    gemm128_body<0>(g1, u2wb, gpre, nullptr, u2b, nullptr, nullptr,
                    DD, 128, 128, 128, DD, idx & 31, idx >> 5, smem);
  }
}

// ---------------- fused: y1 = x + p*sigm(g); out=y1; zbf=bf16(y1*rms*w) -----
__global__ __launch_bounds__(256) void gate_rms_z(
    const float* __restrict__ x, const float* __restrict__ p,
    const float* __restrict__ g, const float* __restrict__ w,
    float* __restrict__ out, u16* __restrict__ zbf)
{
  const int m = blockIdx.x, tid = threadIdx.x;
  const size_t o = (size_t)m*DD + tid*4;
  f32x4 xv = *(const f32x4*)(x+o);
  f32x4 pv = *(const f32x4*)(p+o);
  f32x4 gv = *(const f32x4*)(g+o);
  f32x4 y;
  y.x = xv.x + pv.x * sigm(gv.x);
  y.y = xv.y + pv.y * sigm(gv.y);
  y.z = xv.z + pv.z * sigm(gv.z);
  y.w = xv.w + pv.w * sigm(gv.w);
  *(f32x4*)(out+o) = y;
  float ssum = y.x*y.x + y.y*y.y + y.z*y.z + y.w*y.w;
#pragma unroll
  for (int msk=1; msk<64; msk<<=1) ssum += __shfl_xor(ssum, msk);
  __shared__ float ws[4];
  if ((tid&63)==0) ws[tid>>6] = ssum;
  __syncthreads();
  float inv = 1.f / sqrtf((ws[0]+ws[1]+ws[2]+ws[3])*(1.f/DD) + 1e-6f);
  f32x4 wv = *(const f32x4*)(w + tid*4);
  u16x4 oz;
  oz.x=f2b(y.x*inv*wv.x); oz.y=f2b(y.y*inv*wv.y);
  oz.z=f2b(y.z*inv*wv.z); oz.w=f2b(y.w*inv*wv.w);
  *(u16x4*)(zbf + o) = oz;
}

extern "C" void kernel_launch(void* const* d_in, const int* in_sizes, int n_in,
                              void* d_out, int out_size, void* d_ws, size_t ws_size,
                              hipStream_t stream)
{
  (void)in_sizes; (void)n_in; (void)out_size; (void)ws_size;
  const float* x    = (const float*)d_in[0];
  const float* st0  = (const float*)d_in[1];
  const float* mem0 = (const float*)d_in[2];
  const float* nin  = (const float*)d_in[3];
  const float* cw   = (const float*)d_in[4];
  const float* cb   = (const float*)d_in[5];
  const float* qw   = (const float*)d_in[6];
  const float* kw   = (const float*)d_in[7];
  const float* vw   = (const float*)d_in[8];
  const float* ow   = (const float*)d_in[9];
  const float* sw   = (const float*)d_in[10];
  const float* aupw = (const float*)d_in[11];
  const float* aupb = (const float*)d_in[12];
  const float* adnw = (const float*)d_in[13];
  const float* adnb = (const float*)d_in[14];
  const float* aspk = (const float*)d_in[15];
  const float* betw = (const float*)d_in[16];
  const float* betb = (const float*)d_in[17];
  const float* bspk = (const float*)d_in[18];
  const float* hnw  = (const float*)d_in[19];
  const float* u1w  = (const float*)d_in[20];
  const float* u1b  = (const float*)d_in[21];
  const float* u2w  = (const float*)d_in[22];
  const float* u2b  = (const float*)d_in[23];
  const float* ffnw = (const float*)d_in[24];
  const float* fw1  = (const float*)d_in[25];
  const float* fw3  = (const float*)d_in[26];
  const float* fw2  = (const float*)d_in[27];
  float* out = (float*)d_out;

  char* wsb = (char*)d_ws;
  size_t off = 0;
  auto alloc = [&](size_t bytes)->char*{
    off = (off + 255) & ~(size_t)255;
    char* p = wsb + off; off += bytes; return p;
  };

  // persistent
  u16* wcat4 = (u16*)alloc((size_t)4096*DD*2);   // [qw;kw;vw;sw_hi]
  u16* swcat = (u16*)alloc((size_t)DD*2048*2);   // [swlo | swhi]
  u16* owb   = (u16*)alloc((size_t)DD*DD*2);
  u16* fwcat = (u16*)alloc((size_t)2*DFF*DD*2);  // fw1/fw3 16-row interleave
  u16* fw2b  = (u16*)alloc((size_t)DD*DFF*2);
  u16* aupwb = (u16*)alloc((size_t)128*DD*2);
  u16* adnwb = (u16*)alloc((size_t)DD*128*2);
  u16* betwb = (u16*)alloc((size_t)128*DD*2);
  u16* u1wb  = (u16*)alloc((size_t)128*DD*2);
  u16* u2wb  = (u16*)alloc((size_t)DD*128*2);
  float* aupbp = (float*)alloc(128*4);
  float* betbp = (float*)alloc(128*4);
  float* u1bp  = (float*)alloc(128*4);
  u16* xbf  = (u16*)alloc((size_t)MM*DD*2);
  float* yatt  = (float*)alloc((size_t)MM*DD*4);
  u16* yattb = (u16*)alloc((size_t)MM*DD*2);
  float* invr  = (float*)alloc((size_t)MM*4);

  // early region
  size_t mark = off;
  u16* hcat = (u16*)alloc((size_t)MM*2048*2);    // [h_bf16 | h_lo]
  float* qkvd = (float*)alloc((size_t)MM*SKQ*4); // [q|k|v|drive]
  float* abase = (float*)alloc((size_t)MM*DD*4); // becomes alpha in place
  float* bbase = (float*)alloc((size_t)MM*128*4);
  float* bscale= (float*)alloc((size_t)MM*8*4);
  u64* spk = (u64*)alloc((size_t)BB*HH*TT*2*8);
  u16* gsm  = (u16*)alloc((size_t)MM*128*2);
  u16* g1e  = (u16*)alloc((size_t)MM*128*2);     // gate g1 (persists to fatB)
  float* gpre = (float*)alloc((size_t)MM*DD*4);  // gate pre (persists)
  // late region
  float* proj = (float*)alloc((size_t)MM*DD*4);
  u16* zbf  = (u16*)alloc((size_t)MM*DD*2);
  u16* ffh  = (u16*)alloc((size_t)MM*DFF*2);
  (void)mark;

  dim3 blk(256);

  // fatP: weight/input prep || row_rms
  prep_all<<<dim3(22145 + MM), blk, 0, stream>>>(
      qw, kw, vw, sw, ow, fw1, fw3, fw2, x, aupw, adnw, betw, u1w, u2w,
      aupb, betb, u1b,
      wcat4, swcat, owb, fwcat, fw2b, xbf, aupwb, adnwb, betwb, u1wb, u2wb,
      aupbp, betbp, u1bp, invr);

  conv_silu_k<<<dim3(MM), blk, 0, stream>>>(x, invr, nin, cw, cb, hcat);

  // fused q|k|v|drive_hi projection — 256^2 tile, ring-4 counted pipeline
  gemm256<0><<<dim3(16,16), dim3(512), 0, stream>>>(hcat, wcat4, qkvd, nullptr,
                                                    2048, 2048, DD, SKQ);
  // fatC: drive-lo fix || beta base || qk_norm
  fatC<<<dim3(256 + 32 + MM*HH/4), blk, 0, stream>>>(hcat, swcat, qkvd,
                                                     betwb, bbase, betbp);
  // fatA: spike scan || alpha-up GEMM || gate-u1 GEMM
  fatA<<<dim3(96), blk, 0, stream>>>(qkvd+3072, bbase, bspk, mem0, spk, bscale,
                                     hcat, aupwb, gsm, aupbp,
                                     xbf, u1wb, g1e, u1bp);
  // alpha down-proj with fused spike+sigmoid epilogue
  gemm_bt<4><<<dim3(32,8), blk, 0, stream>>>(gsm, adnwb, abase, nullptr, adnb,
                                             spk, aspk, DD, 128, 128, 128, DD);

  // fatB: delta-rule scan || gate-u2 GEMM
  fatB<<<dim3(512), blk, 0, stream>>>(qkvd, abase, bscale, st0, yatt,
                                      g1e, u2wb, gpre, u2b);
  head_norm_k<<<dim3(MM*HH/4), blk, 0, stream>>>(yatt, hnw, yattb);

  // out proj, then combine(+rms+zscale fused)
  gemm_bt<0><<<dim3(32,8), blk, 0, stream>>>(yattb, owb, proj, nullptr, nullptr,
                                             nullptr, nullptr, DD, DD, DD, DD, DD);
  gate_rms_z<<<dim3(MM), blk, 0, stream>>>(x, proj, gpre, ffnw, out, zbf);

  // FFN: 256^2 swiglu GEMM (ring-4 pipeline), then down-proj accumulate
  gemm256<3><<<dim3(16,32), dim3(512), 0, stream>>>(zbf, fwcat, nullptr, ffh,
                                                    DD, DD, DD, DFF);
  gemm_bt<1><<<dim3(32,8), blk, 0, stream>>>(ffh, fw2b, out, nullptr, nullptr,
                                             nullptr, nullptr, DD, DFF, DFF, DFF, DD);
}

// Round 27
// 659.433 us; speedup vs baseline: 1.0562x; 1.0562x over previous
//
#include <hip/hip_runtime.h>
#include <hip/hip_bf16.h>
#include <stdint.h>

#define DEV static __device__ __forceinline__

typedef float f32x4 __attribute__((ext_vector_type(4)));
typedef short bf16x8 __attribute__((ext_vector_type(8)));
typedef float accf4 __attribute__((ext_vector_type(4)));
typedef unsigned short u16;
typedef unsigned int u32;
typedef unsigned long long u64;
typedef u16 u16x4 __attribute__((ext_vector_type(4)));

#define BB 4
#define TT 1024
#define DD 1024
#define HH 8
#define DKK 128
#define DVV 128
#define MM (BB*TT)
#define DFF 4096
#define SKQ 4096   // qkvd row stride

DEV u16 f2b(float f){
  union { float f; u32 u; } v; v.f = f;
  u32 r = (v.u + 0x7fffu + ((v.u >> 16) & 1u)) >> 16;
  return (u16)r;
}
DEV float b2f(u16 h){
  union { u32 u; float f; } v; v.u = ((u32)h) << 16;
  return v.f;
}
DEV float sigm(float x){ return 1.f / (1.f + __expf(-x)); }
DEV float silu_f(float x){ return x / (1.f + __expf(-x)); }

DEV void gl_lds16(const void* g, void* l){
  __builtin_amdgcn_global_load_lds(
      (const __attribute__((address_space(1))) void*)g,
      (__attribute__((address_space(3))) void*)l, 16, 0, 0);
}

// ---- DPP cross-lane adds ----
template<int CTRL>
DEV float dpp_add(float x){
  union { float f; int i; } u; u.f = x;
  int y = __builtin_amdgcn_update_dpp(0, u.i, CTRL, 0xf, 0xf, true);
  union { int i; float f; } w; w.i = y;
  return x + w.f;
}
DEV float red16(float x){
  x = dpp_add<0xB1>(x);
  x = dpp_add<0x4E>(x);
  x = dpp_add<0x141>(x);
  x = dpp_add<0x140>(x);
  return x;
}
DEV float red64_last(float x){
  x = red16(x);
  x = dpp_add<0x142>(x);
  x = dpp_add<0x143>(x);
  return x;
}

// ---------------- GEMM 128x128 body (shared by gemm_bt + fat kernels) ------
// 2-phase schedule (best-measured for this body; R24's depth-2 regressed).
// OP 0: C=acc(+bias)   OP 1: C+=acc   OP 2: Cb=bf16(silu(acc+bias))
// OP 3: interleaved swiglu epilogue   OP 4: alpha epilogue
template<int OP>
DEV void gemm128_body(
    const u16* __restrict__ A, const u16* __restrict__ Bm,
    float* __restrict__ C, u16* __restrict__ Cb,
    const float* __restrict__ bias,
    const u64* __restrict__ spkp, const float* __restrict__ aspkp,
    int N, int K, int lda, int ldb, int ldc,
    int bm, int bn, char* smem)
{
  u16* lsA0 = (u16*)smem;
  u16* lsA1 = (u16*)(smem + 16384);
  u16* lsB0 = (u16*)(smem + 32768);
  u16* lsB1 = (u16*)(smem + 49152);
  const int tid = threadIdx.x;
  const int wid = tid >> 6, lane = tid & 63;
  const int wr = wid >> 1, wc = wid & 1;
  const int fr = lane & 15, fq = lane >> 4;
  accf4 acc[4][4];
#pragma unroll
  for (int i=0;i<4;i++)
#pragma unroll
    for (int j=0;j<4;j++) acc[i][j] = (accf4)0.f;

  const int srow = tid >> 3;
  const int sk = (tid & 7) * 8;
  const u16* aP = A + (size_t)(bm*128 + srow) * lda + sk;
  const u16* bP = Bm + (size_t)(bn*128 + srow) * ldb + sk;

  auto STAGE = [&](int buf, int t){
    char* lA = (char*)(buf ? lsA1 : lsA0) + tid*16;
    char* lB = (char*)(buf ? lsB1 : lsB0) + tid*16;
    const u16* a = aP + (size_t)t*64;
    const u16* b = bP + (size_t)t*64;
#pragma unroll
    for (int it=0; it<4; ++it) {
      gl_lds16(a + (size_t)it*32*lda, lA + it*4096);
      gl_lds16(b + (size_t)it*32*ldb, lB + it*4096);
    }
  };

  const int nk = K >> 6;
  STAGE(0, 0);
  asm volatile("s_waitcnt vmcnt(0)" ::: "memory");
  __syncthreads();
  int cur = 0;
  for (int t = 0; t < nk; ++t) {
    if (t + 1 < nk) STAGE(cur ^ 1, t + 1);
    const u16* la = cur ? lsA1 : lsA0;
    const u16* lb = cur ? lsB1 : lsB0;
#pragma unroll
    for (int ks=0; ks<2; ++ks) {
      bf16x8 av[4], bv[4];
#pragma unroll
      for (int i=0;i<4;i++)
        av[i] = *(const bf16x8*)&la[(wr*64 + i*16 + fr)*64 + ks*32 + fq*8];
#pragma unroll
      for (int j=0;j<4;j++)
        bv[j] = *(const bf16x8*)&lb[(wc*64 + j*16 + fr)*64 + ks*32 + fq*8];
#pragma unroll
      for (int i=0;i<4;i++)
#pragma unroll
        for (int j=0;j<4;j++)
          acc[i][j] = __builtin_amdgcn_mfma_f32_16x16x32_bf16(av[i], bv[j], acc[i][j], 0, 0, 0);
    }
    asm volatile("s_waitcnt vmcnt(0)" ::: "memory");
    __syncthreads();
    cur ^= 1;
  }

  if constexpr (OP == 3) {
#pragma unroll
    for (int i=0;i<4;i++) {
      const int r0 = bm*128 + wr*64 + i*16 + fq*4;
#pragma unroll
      for (int j=0;j<4;j+=2) {
        const int oc = bn*64 + wc*32 + (j>>1)*16 + fr;
#pragma unroll
        for (int rr=0; rr<4; ++rr) {
          Cb[(size_t)(r0+rr)*ldc + oc] =
              f2b(silu_f(acc[i][j][rr]) * acc[i][j+1][rr]);
        }
      }
    }
  } else if constexpr (OP == 4) {
#pragma unroll
    for (int i=0;i<4;i++) {
      const int r0 = bm*128 + wr*64 + i*16 + fq*4;
#pragma unroll
      for (int j=0;j<4;j++) {
        const int c = bn*128 + wc*64 + j*16 + fr;
        const int hq = c >> 7, dkh = c & 127;
        const float asv = aspkp[c];
        const float bv = bias[c];
#pragma unroll
        for (int rr=0; rr<4; ++rr) {
          const int r = r0 + rr;
          const int bq = r >> 10, tq = r & 1023;
          const u64 mask = spkp[(((size_t)(bq*8 + hq))*TT + tq)*2 + (dkh>>6)];
          const float add = ((mask >> (dkh & 63)) & 1ull) ? asv : 0.f;
          C[(size_t)r*ldc + c] = sigm(acc[i][j][rr] + bv + add);
        }
      }
    }
  } else {
#pragma unroll
    for (int i=0;i<4;i++) {
      const int r0 = bm*128 + wr*64 + i*16 + fq*4;
#pragma unroll
      for (int j=0;j<4;j++) {
        const int c = bn*128 + wc*64 + j*16 + fr;
#pragma unroll
        for (int rr=0; rr<4; ++rr) {
          const size_t idx = (size_t)(r0+rr)*ldc + c;
          float v = acc[i][j][rr];
          if (OP == 0) { if (bias) v += bias[c]; C[idx] = v; }
          if (OP == 1) { C[idx] += v; }
          if (OP == 2) { v += bias[c]; Cb[idx] = f2b(silu_f(v)); }
        }
      }
    }
  }
}

template<int OP>
__global__ __launch_bounds__(256) void gemm_bt(
    const u16* __restrict__ A, const u16* __restrict__ Bm,
    float* __restrict__ C, u16* __restrict__ Cb,
    const float* __restrict__ bias,
    const u64* __restrict__ spkp, const float* __restrict__ aspkp,
    int N, int K, int lda, int ldb, int ldc)
{
  __shared__ __align__(16) char smem[65536];
  gemm128_body<OP>(A, Bm, C, Cb, bias, spkp, aspkp, N, K, lda, ldb, ldc,
                   blockIdx.x, blockIdx.y, smem);
}

// ---------------- GEMM 256x256: ring-4 half-tile counted pipeline ----------
// T3/T4: K split into 32-wide halves; 4 LDS half-slots (32KB each, 128KB
// total). Phase p: STAGE h(p+2)->slot (p+2)&3 (4 loads/thr); vmcnt(8)
// [outstanding = h(p+1)+h(p+2) = 8 -> drains exactly h(p), NEVER 0 in main
// loop]; barrier; 12 ds_read_b128 + 32 MFMA on h(p). Loads get ~2 phases of
// lead time. Epilogue peels vmcnt(4)/vmcnt(0). R26's run was confounded by a
// K=2048 call-site bug (doubled qkvd work + OOB lo-half reads, absmax tell);
// this round re-tests ring-4 with the correct K=1024 call.
// OP 0: C=acc   OP 3: swiglu interleave epilogue (fwcat pairing)
template<int OP>
__global__ __launch_bounds__(512) void gemm256(
    const u16* __restrict__ A, const u16* __restrict__ Bm,
    float* __restrict__ C, u16* __restrict__ Cb,
    int K, int lda, int ldb, int ldc)
{
  __shared__ u16 lsA[4][256*32];   // 4 half-slots x 16KB
  __shared__ u16 lsB[4][256*32];
  const int tid = threadIdx.x;
  const int bm = blockIdx.x, bn = blockIdx.y;
  const int wid = tid >> 6, lane = tid & 63;
  const int wr = wid >> 2, wc = wid & 3;
  const int fr = lane & 15, fq = lane >> 4;
  accf4 acc[8][4];
#pragma unroll
  for (int i=0;i<8;i++)
#pragma unroll
    for (int j=0;j<4;j++) acc[i][j] = (accf4)0.f;

  const int srow = tid >> 2;          // 0..127 (4 threads/row cover 32 cols)
  const int sk = (tid & 3) * 8;
  const u16* aP = A + (size_t)(bm*256 + srow) * lda + sk;
  const u16* bP = Bm + (size_t)(bn*256 + srow) * ldb + sk;

  // stage K-half h (global k-offset h*32) into slot s: 4 gl_lds16/thread
  auto STAGE = [&](int s, int h){
    char* lA = (char*)lsA[s] + tid*16;
    char* lB = (char*)lsB[s] + tid*16;
    const u16* a = aP + (size_t)h*32;
    const u16* b = bP + (size_t)h*32;
#pragma unroll
    for (int it=0; it<2; ++it) {
      gl_lds16(a + (size_t)it*128*lda, lA + it*8192);
      gl_lds16(b + (size_t)it*128*ldb, lB + it*8192);
    }
  };

  // compute one K=32 half from slot s: 12 ds_read_b128 + 32 MFMA
  auto COMPUTE = [&](int s){
    bf16x8 av[8], bv[4];
#pragma unroll
    for (int i=0;i<8;i++)
      av[i] = *(const bf16x8*)&lsA[s][(wr*128 + i*16 + fr)*32 + fq*8];
#pragma unroll
    for (int j=0;j<4;j++)
      bv[j] = *(const bf16x8*)&lsB[s][(wc*64 + j*16 + fr)*32 + fq*8];
#pragma unroll
    for (int i=0;i<8;i++)
#pragma unroll
      for (int j=0;j<4;j++)
        acc[i][j] = __builtin_amdgcn_mfma_f32_16x16x32_bf16(av[i], bv[j], acc[i][j], 0, 0, 0);
  };

  const int NH = K >> 5;              // halves; >= 32 at all call sites
  STAGE(0, 0);
  STAGE(1, 1);
  for (int p = 0; p < NH - 2; ++p) {
    STAGE((p + 2) & 3, p + 2);
    asm volatile("s_waitcnt vmcnt(8)" ::: "memory");
    __syncthreads();
    COMPUTE(p & 3);
  }
  asm volatile("s_waitcnt vmcnt(4)" ::: "memory");
  __syncthreads();
  COMPUTE((NH - 2) & 3);
  asm volatile("s_waitcnt vmcnt(0)" ::: "memory");
  __syncthreads();
  COMPUTE((NH - 1) & 3);

  if constexpr (OP == 3) {
#pragma unroll
    for (int i=0;i<8;i++) {
      const int r0 = bm*256 + wr*128 + i*16 + fq*4;
#pragma unroll
      for (int j=0;j<4;j+=2) {
        const int rb = bn*256 + wc*64 + j*16 + fr;
        const int oc = (rb>>7)*64 + (((rb>>4)&7)>>1)*16 + (rb&15);
#pragma unroll
        for (int rr=0; rr<4; ++rr) {
          Cb[(size_t)(r0+rr)*ldc + oc] =
              f2b(silu_f(acc[i][j][rr]) * acc[i][j+1][rr]);
        }
      }
    }
  } else {
#pragma unroll
    for (int i=0;i<8;i++) {
      const int r0 = bm*256 + wr*128 + i*16 + fq*4;
#pragma unroll
      for (int j=0;j<4;j++) {
        const int c = bn*256 + wc*64 + j*16 + fr;
#pragma unroll
        for (int rr=0; rr<4; ++rr)
          C[(size_t)(r0+rr)*ldc + c] = acc[i][j][rr];
      }
    }
  }
}

// ---------------- fatP: weight/input prep (22145) | row_rms (4096) ---------
__global__ __launch_bounds__(256) void prep_all(
    const float* __restrict__ qw, const float* __restrict__ kw,
    const float* __restrict__ vw, const float* __restrict__ sw,
    const float* __restrict__ ow, const float* __restrict__ fw1,
    const float* __restrict__ fw3, const float* __restrict__ fw2,
    const float* __restrict__ x, const float* __restrict__ aupw,
    const float* __restrict__ adnw, const float* __restrict__ betw,
    const float* __restrict__ u1w, const float* __restrict__ u2w,
    const float* __restrict__ aupb, const float* __restrict__ betb,
    const float* __restrict__ u1b,
    u16* __restrict__ wcat4, u16* __restrict__ swcat, u16* __restrict__ owb,
    u16* __restrict__ fwcat, u16* __restrict__ fw2b, u16* __restrict__ xbf,
    u16* __restrict__ aupwb, u16* __restrict__ adnwb, u16* __restrict__ betwb,
    u16* __restrict__ u1wb, u16* __restrict__ u2wb,
    float* __restrict__ aupbp, float* __restrict__ betbp, float* __restrict__ u1bp,
    float* __restrict__ invr)
{
  const int bid = blockIdx.x, tid = threadIdx.x;
  auto cvt4 = [&](const float* s, u16* d, int base){
    size_t i = ((size_t)(bid - base)*256 + tid)*4;
    f32x4 v = *(const f32x4*)(s + i);
    u16x4 o; o.x=f2b(v.x); o.y=f2b(v.y); o.z=f2b(v.z); o.w=f2b(v.w);
    *(u16x4*)(d + i) = o;
  };
  auto pad4 = [&](const float* s, u16* d, int base, int sr, int sc, int dc){
    size_t i = ((size_t)(bid - base)*256 + tid)*4;
    int r = (int)(i / dc), c = (int)(i % dc);
    u16x4 o;
#pragma unroll
    for (int e=0;e<4;e++){
      float v = (r < sr && c+e < sc) ? s[(size_t)r*sc + c + e] : 0.f;
      o[e] = f2b(v);
    }
    *(u16x4*)(d + i) = o;
  };
  if (bid < 1024)       cvt4(qw, wcat4, 0);
  else if (bid < 2048)  cvt4(kw, wcat4 + (size_t)1024*1024, 1024);
  else if (bid < 3072)  cvt4(vw, wcat4 + (size_t)2*1024*1024, 2048);
  else if (bid < 4096) {
    size_t i = ((size_t)(bid - 3072)*256 + tid)*4;
    int r = (int)(i >> 10), c = (int)(i & 1023);
    f32x4 v = *(const f32x4*)(sw + i);
    u16x4 h, l;
    h.x=f2b(v.x); h.y=f2b(v.y); h.z=f2b(v.z); h.w=f2b(v.w);
    l.x=f2b(v.x-b2f(h.x)); l.y=f2b(v.y-b2f(h.y)); l.z=f2b(v.z-b2f(h.z)); l.w=f2b(v.w-b2f(h.w));
    *(u16x4*)(wcat4 + (size_t)3*1024*1024 + i) = h;
    *(u16x4*)(swcat + (size_t)r*2048 + 1024 + c) = h;
    *(u16x4*)(swcat + (size_t)r*2048 + c) = l;
  }
  else if (bid < 5120)  cvt4(ow, owb, 4096);
  else if (bid < 13312) {
    int r = bid - 5120;                 // [0, 8192)
    int t128 = r >> 7, s8 = (r >> 4) & 7, row16 = r & 15;
    int srow = t128*64 + (s8 >> 1)*16 + row16;
    const float* src = (s8 & 1) ? fw3 : fw1;
    size_t si = (size_t)srow*1024 + tid*4;
    f32x4 v = *(const f32x4*)(src + si);
    u16x4 o; o.x=f2b(v.x); o.y=f2b(v.y); o.z=f2b(v.z); o.w=f2b(v.w);
    *(u16x4*)(fwcat + (size_t)r*1024 + tid*4) = o;
  }
  else if (bid < 17408) cvt4(fw2, fw2b, 13312);
  else if (bid < 21504) cvt4(x, xbf, 17408);
  else if (bid < 21632) pad4(aupw, aupwb, 21504, 64, 1024, 1024);
  else if (bid < 21760) pad4(adnw, adnwb, 21632, 1024, 64, 128);
  else if (bid < 21888) pad4(betw, betwb, 21760, 8, 1024, 1024);
  else if (bid < 22016) pad4(u1w, u1wb, 21888, 64, 1024, 1024);
  else if (bid < 22144) pad4(u2w, u2wb, 22016, 1024, 64, 128);
  else if (bid == 22144) {
    if (tid < 128) {
      aupbp[tid] = tid < 64 ? aupb[tid] : 0.f;
      betbp[tid] = tid < 8  ? betb[tid] : 0.f;
      u1bp[tid]  = tid < 64 ? u1b[tid]  : 0.f;
    }
  }
  else {
    // row_rms for row m = bid - 22145
    int m = bid - 22145;
    f32x4 v = *(const f32x4*)(x + (size_t)m*DD + tid*4);
    float s = v.x*v.x + v.y*v.y + v.z*v.z + v.w*v.w;
#pragma unroll
    for (int msk=1; msk<64; msk<<=1) s += __shfl_xor(s, msk);
    __shared__ float ws[4];
    if ((tid&63)==0) ws[tid>>6] = s;
    __syncthreads();
    if (tid==0) invr[m] = 1.f / sqrtf((ws[0]+ws[1]+ws[2]+ws[3])*(1.f/DD) + 1e-6f);
  }
}

// ---------------- norm + causal conv + silu -> bf16 [hi|lo] cat ------------
__global__ __launch_bounds__(256) void conv_silu_k(
    const float* __restrict__ x, const float* __restrict__ invr,
    const float* __restrict__ nw, const float* __restrict__ cw, const float* __restrict__ cb,
    u16* __restrict__ hcat)
{
  int m = blockIdx.x, tid = threadIdx.x;
  int b = m >> 10, t = m & 1023;
  int d4 = tid * 4;
  f32x4 acc = *(const f32x4*)(cb + d4);
  f32x4 nwv = *(const f32x4*)(nw + d4);
  f32x4 w0 = *(const f32x4*)(cw + (size_t)(d4+0)*4);
  f32x4 w1 = *(const f32x4*)(cw + (size_t)(d4+1)*4);
  f32x4 w2 = *(const f32x4*)(cw + (size_t)(d4+2)*4);
  f32x4 w3 = *(const f32x4*)(cw + (size_t)(d4+3)*4);
#pragma unroll
  for (int j=0;j<4;j++) {
    int tt = t - 3 + j;
    if (tt >= 0) {
      int m2 = (b<<10) + tt;
      f32x4 xv = *(const f32x4*)(x + (size_t)m2*DD + d4);
      float sc = invr[m2];
      acc.x += xv.x * sc * nwv.x * w0[j];
      acc.y += xv.y * sc * nwv.y * w1[j];
      acc.z += xv.z * sc * nwv.z * w2[j];
      acc.w += xv.w * sc * nwv.w * w3[j];
    }
  }
  float h0 = silu_f(acc.x), h1 = silu_f(acc.y), h2 = silu_f(acc.z), h3 = silu_f(acc.w);
  size_t o = (size_t)m*2048 + d4;
  u16x4 hv; hv.x=f2b(h0); hv.y=f2b(h1); hv.z=f2b(h2); hv.w=f2b(h3);
  u16x4 lv; lv.x=f2b(h0-b2f(hv.x)); lv.y=f2b(h1-b2f(hv.y)); lv.z=f2b(h2-b2f(hv.z)); lv.w=f2b(h3-b2f(hv.w));
  *(u16x4*)(hcat + o) = hv;
  *(u16x4*)(hcat + o + 1024) = lv;
}

// ---------------- q/k L2 normalization body (stride 4096) ------------------
DEV void qknorm_body(int gwblk, float* __restrict__ qkv){
  int gw = gwblk*4 + (threadIdx.x>>6);
  int lane = threadIdx.x & 63;
  size_t off = (size_t)(gw>>3)*SKQ + (size_t)(gw&7)*DKK;
  float* q = qkv + off;
  float* k = qkv + off + 1024;
  float q1 = q[lane], q2 = q[lane+64];
  float k1 = k[lane], k2 = k[lane+64];
  float sq = q1*q1+q2*q2, sk = k1*k1+k2*k2;
#pragma unroll
  for (int msk=1; msk<64; msk<<=1){ sq += __shfl_xor(sq,msk); sk += __shfl_xor(sk,msk); }
  float iq = 1.f/(sqrtf(sq)+1e-6f), ik = 1.f/(sqrtf(sk)+1e-6f);
  q[lane]=q1*iq; q[lane+64]=q2*iq;
  k[lane]=k1*ik; k[lane+64]=k2*ik;
}

// ---------------- headwise RMSNorm -> bf16 ---------------------------------
__global__ __launch_bounds__(256) void head_norm_k(
    const float* __restrict__ y, const float* __restrict__ w, u16* __restrict__ o)
{
  int gw = blockIdx.x*4 + (threadIdx.x>>6);
  int lane = threadIdx.x & 63;
  int h = gw & 7;
  size_t off = (size_t)(gw>>3)*DD + (size_t)h*DVV;
  float y1 = y[off+lane], y2 = y[off+lane+64];
  float s = y1*y1 + y2*y2;
#pragma unroll
  for (int msk=1; msk<64; msk<<=1) s += __shfl_xor(s,msk);
  float inv = 1.f / sqrtf(s*(1.f/DVV) + 1e-6f);
  o[off+lane]    = f2b(y1*inv*w[h*DVV+lane]);
  o[off+lane+64] = f2b(y2*inv*w[h*DVV+lane+64]);
}

// ---------------- LIF spike scan body (LDS-DMA double buffer) --------------
DEV void spike_body(
    int bh, char* smem,
    const float* __restrict__ dr, const float* __restrict__ bbase,
    const float* __restrict__ bspk, const float* __restrict__ mem0,
    u64* __restrict__ spk, float* __restrict__ bs)
{
  const int tid = threadIdx.x;
  if (tid >= 64) return;               // one wave does the scan
  float* bufA = (float*)smem;          // 32KB
  float* bufB = (float*)(smem + 32768);// 32KB
  float* bb_lds = (float*)(smem + 65536); // 4KB
  const int b = bh>>3, h = bh&7;
  const int lane = tid;

  for (int i=0;i<16;++i)
    bb_lds[i*64 + lane] = bbase[((size_t)b*TT + i*64 + lane)*128 + h];

  float m1 = mem0[bh*DKK + lane], m2 = mem0[bh*DKK + lane + 64];
  const float b1s = bspk[h*DKK+lane], b2s = bspk[h*DKK+lane+64];

  const char* drBase = (const char*)(dr + ((size_t)b*TT)*SKQ + (size_t)h*DKK);
  const int rowp = lane>>5, col = lane&31;
  asm volatile("s_waitcnt vmcnt(0) lgkmcnt(0)" ::: "memory");

  auto DMA = [&](int c){
    char* l = (char*)((c&1) ? bufB : bufA);
    const char* g = drBase + ((size_t)(c*64 + rowp)*SKQ + (size_t)col*4)*4;
#pragma unroll
    for (int j=0;j<32;++j)
      gl_lds16(g + (size_t)j*2*SKQ*4, l + j*1024);
  };

  auto CHUNK = [&](int c){
    const float* lf = (c&1) ? bufB : bufA;
    u32 q0=0,q1=0,q2=0,q3=0; float qss=0.f;
#pragma unroll 8
    for (int t=0;t<64;++t){
      float d1 = lf[t*128 + lane];
      float d2 = lf[t*128 + 64 + lane];
      m1 = 0.9f*m1 + d1; m2 = 0.9f*m2 + d2;
      bool p1 = m1 > 0.5f, p2 = m2 > 0.5f;
      u64 bl1 = __ballot(p1), bl2 = __ballot(p2);
      float sp1 = p1 ? 1.f : 0.f, sp2 = p2 ? 1.f : 0.f;
      m1 -= sp1*0.5f; m2 -= sp2*0.5f;
      float ss = red64_last(sp1*b1s + sp2*b2s);
      float ssv = __shfl(ss, 63);
      if (lane == t){
        q0=(u32)bl1; q1=(u32)(bl1>>32);
        q2=(u32)bl2; q3=(u32)(bl2>>32);
        qss=ssv;
      }
    }
    const int tg = c*64 + lane;
    float bv = bb_lds[tg];
    bool act = (q0|q1|q2|q3) != 0u;
    float beta = act ? sigm(bv + qss) : 0.f;
    u32* sp32 = (u32*)(spk + ((size_t)bh*TT + tg)*2);
    uint4 m4; m4.x=q0; m4.y=q1; m4.z=q2; m4.w=q3;
    *(uint4*)sp32 = m4;
    bs[((size_t)b*TT + tg)*HH + h] = beta;
  };

  DMA(0); DMA(1);
  for (int c=0; c<16; ++c){
    if (c == 0)       asm volatile("s_waitcnt vmcnt(32)" ::: "memory");
    else if (c < 15)  asm volatile("s_waitcnt vmcnt(34)" ::: "memory");
    else              asm volatile("s_waitcnt vmcnt(2)"  ::: "memory");
    CHUNK(c);
    if (c+2 < 16) DMA(c+2);
  }
}

// ---------------- gated delta-rule scan body (R10/R17/R19 best) ------------
DEV void scan_body(
    int bx,
    const float* __restrict__ qkv, const float* __restrict__ al,
    const float* __restrict__ bs, const float* __restrict__ s0p,
    float* __restrict__ y)
{
  const int bh = bx & 31, dvb = bx >> 5;
  const int b = bh >> 3, h = bh & 7;
  const int tid = threadIdx.x;
  const int dvl = tid >> 4, dkl = tid & 15;
  const int dv = dvb*16 + dvl;
  const int dk0 = dkl*8;

  float s[8];
  {
    const float* sp = s0p + ((size_t)bh*DKK + dk0) * DVV + dv;
#pragma unroll
    for (int i=0;i<8;i++) s[i] = sp[(size_t)i*DVV];
  }
  const size_t rq = ((size_t)b*TT)*SKQ + (size_t)h*DKK;
  const size_t ra = ((size_t)b*TT)*DD + (size_t)h*DKK;
  const float* qP = qkv + rq + dk0;
  const float* kP = qkv + rq + 1024 + dk0;
  const float* vP = qkv + rq + 2048 + dv;
  const float* aP = al + ra + dk0;
  const float* bP = bs + (size_t)b*TT*HH + h;
  float* yP = y + ra + dv;

  struct Buf { f32x4 kk[2], qq[2], aa[2]; float vv, bb; };
  Buf B0,B1,B2,B3,B4,B5,B6,B7;
  auto LOAD = [&](int t_, Buf& Bx){
    size_t o = (size_t)t_*SKQ;
    size_t oa = (size_t)t_*DD;
    Bx.kk[0] = *(const f32x4*)(kP + o); Bx.kk[1] = *(const f32x4*)(kP + o + 4);
    Bx.qq[0] = *(const f32x4*)(qP + o); Bx.qq[1] = *(const f32x4*)(qP + o + 4);
    Bx.aa[0] = *(const f32x4*)(aP + oa); Bx.aa[1] = *(const f32x4*)(aP + oa + 4);
    Bx.vv = vP[o];
    Bx.bb = bP[(size_t)t_*HH];
  };
  auto STEP = [&](const Buf& Bx, int t_){
    float pp = 0.f, pp2 = 0.f;
#pragma unroll
    for (int i=0;i<2;i++)
#pragma unroll
      for (int e=0;e<4;e++){
        float sv = s[i*4+e] * Bx.aa[i][e];
        s[i*4+e] = sv;
        if (e < 2) pp += sv * Bx.kk[i][e]; else pp2 += sv * Bx.kk[i][e];
      }
    pp = red16(pp + pp2);
    float err = Bx.bb * (Bx.vv - pp);
    float oo = 0.f, oo2 = 0.f;
#pragma unroll
    for (int i=0;i<2;i++)
#pragma unroll
      for (int e=0;e<4;e++){
        float sv = s[i*4+e] + Bx.kk[i][e] * err;
        s[i*4+e] = sv;
        if (e < 2) oo += sv * Bx.qq[i][e]; else oo2 += sv * Bx.qq[i][e];
      }
    oo = red16(oo + oo2);
    if (dkl == 0) yP[(size_t)t_*DD] = oo;
  };

#define SBAR __builtin_amdgcn_sched_barrier(0)
  LOAD(0,B0); LOAD(1,B1); LOAD(2,B2); LOAD(3,B3);
  LOAD(4,B4); LOAD(5,B5); LOAD(6,B6);
  SBAR;
  for (int t=0; t<TT; t+=8){
    LOAD(t+ 7 < TT ? t+ 7 : TT-1, B7); SBAR; STEP(B0, t);   SBAR;
    LOAD(t+ 8 < TT ? t+ 8 : TT-1, B0); SBAR; STEP(B1, t+1); SBAR;
    LOAD(t+ 9 < TT ? t+ 9 : TT-1, B1); SBAR; STEP(B2, t+2); SBAR;
    LOAD(t+10 < TT ? t+10 : TT-1, B2); SBAR; STEP(B3, t+3); SBAR;
    LOAD(t+11 < TT ? t+11 : TT-1, B3); SBAR; STEP(B4, t+4); SBAR;
    LOAD(t+12 < TT ? t+12 : TT-1, B4); SBAR; STEP(B5, t+5); SBAR;
    LOAD(t+13 < TT ? t+13 : TT-1, B5); SBAR; STEP(B6, t+6); SBAR;
    LOAD(t+14 < TT ? t+14 : TT-1, B6); SBAR; STEP(B7, t+7); SBAR;
  }
#undef SBAR
}

// ---------------- fatA: spike_scan(32) | aup GEMM(32) | u1 GEMM(32) --------
__global__ __launch_bounds__(256) void fatA(
    const float* __restrict__ dr, const float* __restrict__ bbase,
    const float* __restrict__ bspk, const float* __restrict__ mem0,
    u64* __restrict__ spk, float* __restrict__ bs,
    const u16* __restrict__ hcat, const u16* __restrict__ aupwb,
    u16* __restrict__ gsm, const float* __restrict__ aupbp,
    const u16* __restrict__ xbf, const u16* __restrict__ u1wb,
    u16* __restrict__ g1, const float* __restrict__ u1bp)
{
  __shared__ __align__(16) char smem[69632];
  const int bx = blockIdx.x;
  if (bx < 32) {
    spike_body(bx, smem, dr, bbase, bspk, mem0, spk, bs);
  } else if (bx < 64) {
    gemm128_body<2>(hcat, aupwb, nullptr, gsm, aupbp, nullptr, nullptr,
                    128, DD, 2048, DD, 128, bx - 32, 0, smem);
  } else {
    gemm128_body<2>(xbf, u1wb, nullptr, g1, u1bp, nullptr, nullptr,
                    128, DD, DD, DD, 128, bx - 64, 0, smem);
  }
}

// ---------------- fatC: drive-lo GEMM(256) | beta GEMM(32) | qk_norm(8192) --
// drive-lo accumulates into qkvd cols 3072+ (depends on qkvd gemm); beta and
// qk_norm (cols 0..2047) are disjoint/independent — all safely co-dispatched.
__global__ __launch_bounds__(256) void fatC(
    const u16* __restrict__ hcat, const u16* __restrict__ swcat,
    float* __restrict__ qkvd,
    const u16* __restrict__ betwb, float* __restrict__ bbase,
    const float* __restrict__ betbp)
{
  __shared__ __align__(16) char smem[65536];
  const int bx = blockIdx.x;
  if (bx < 256) {
    gemm128_body<1>(hcat, swcat, qkvd + 3072, nullptr, nullptr, nullptr, nullptr,
                    DD, 2048, 2048, 2048, SKQ, bx & 31, bx >> 5, smem);
  } else if (bx < 288) {
    gemm128_body<0>(hcat, betwb, bbase, nullptr, betbp, nullptr, nullptr,
                    128, DD, 2048, DD, 128, bx - 256, 0, smem);
  } else {
    qknorm_body(bx - 288, qkvd);
  }
}

// ---------------- fatB: scan_k(256) | u2 GEMM(256) -------------------------
__global__ __launch_bounds__(256) void fatB(
    const float* __restrict__ qkv, const float* __restrict__ al,
    const float* __restrict__ bs, const float* __restrict__ s0p,
    float* __restrict__ y,
    const u16* __restrict__ g1, const u16* __restrict__ u2wb,
    float* __restrict__ gpre, const float* __restrict__ u2b)
{
  __shared__ __align__(16) char smem[65536];
  const int bx = blockIdx.x;
  if (bx < 256) {
    scan_body(bx, qkv, al, bs, s0p, y);
  } else {
    const int idx = bx - 256;
    gemm128_body<0>(g1, u2wb, gpre, nullptr, u2b, nullptr, nullptr,
                    DD, 128, 128, 128, DD, idx & 31, idx >> 5, smem);
  }
}

// ---------------- fused: y1 = x + p*sigm(g); out=y1; zbf=bf16(y1*rms*w) -----
__global__ __launch_bounds__(256) void gate_rms_z(
    const float* __restrict__ x, const float* __restrict__ p,
    const float* __restrict__ g, const float* __restrict__ w,
    float* __restrict__ out, u16* __restrict__ zbf)
{
  const int m = blockIdx.x, tid = threadIdx.x;
  const size_t o = (size_t)m*DD + tid*4;
  f32x4 xv = *(const f32x4*)(x+o);
  f32x4 pv = *(const f32x4*)(p+o);
  f32x4 gv = *(const f32x4*)(g+o);
  f32x4 y;
  y.x = xv.x + pv.x * sigm(gv.x);
  y.y = xv.y + pv.y * sigm(gv.y);
  y.z = xv.z + pv.z * sigm(gv.z);
  y.w = xv.w + pv.w * sigm(gv.w);
  *(f32x4*)(out+o) = y;
  float ssum = y.x*y.x + y.y*y.y + y.z*y.z + y.w*y.w;
#pragma unroll
  for (int msk=1; msk<64; msk<<=1) ssum += __shfl_xor(ssum, msk);
  __shared__ float ws[4];
  if ((tid&63)==0) ws[tid>>6] = ssum;
  __syncthreads();
  float inv = 1.f / sqrtf((ws[0]+ws[1]+ws[2]+ws[3])*(1.f/DD) + 1e-6f);
  f32x4 wv = *(const f32x4*)(w + tid*4);
  u16x4 oz;
  oz.x=f2b(y.x*inv*wv.x); oz.y=f2b(y.y*inv*wv.y);
  oz.z=f2b(y.z*inv*wv.z); oz.w=f2b(y.w*inv*wv.w);
  *(u16x4*)(zbf + o) = oz;
}

extern "C" void kernel_launch(void* const* d_in, const int* in_sizes, int n_in,
                              void* d_out, int out_size, void* d_ws, size_t ws_size,
                              hipStream_t stream)
{
  (void)in_sizes; (void)n_in; (void)out_size; (void)ws_size;
  const float* x    = (const float*)d_in[0];
  const float* st0  = (const float*)d_in[1];
  const float* mem0 = (const float*)d_in[2];
  const float* nin  = (const float*)d_in[3];
  const float* cw   = (const float*)d_in[4];
  const float* cb   = (const float*)d_in[5];
  const float* qw   = (const float*)d_in[6];
  const float* kw   = (const float*)d_in[7];
  const float* vw   = (const float*)d_in[8];
  const float* ow   = (const float*)d_in[9];
  const float* sw   = (const float*)d_in[10];
  const float* aupw = (const float*)d_in[11];
  const float* aupb = (const float*)d_in[12];
  const float* adnw = (const float*)d_in[13];
  const float* adnb = (const float*)d_in[14];
  const float* aspk = (const float*)d_in[15];
  const float* betw = (const float*)d_in[16];
  const float* betb = (const float*)d_in[17];
  const float* bspk = (const float*)d_in[18];
  const float* hnw  = (const float*)d_in[19];
  const float* u1w  = (const float*)d_in[20];
  const float* u1b  = (const float*)d_in[21];
  const float* u2w  = (const float*)d_in[22];
  const float* u2b  = (const float*)d_in[23];
  const float* ffnw = (const float*)d_in[24];
  const float* fw1  = (const float*)d_in[25];
  const float* fw3  = (const float*)d_in[26];
  const float* fw2  = (const float*)d_in[27];
  float* out = (float*)d_out;

  char* wsb = (char*)d_ws;
  size_t off = 0;
  auto alloc = [&](size_t bytes)->char*{
    off = (off + 255) & ~(size_t)255;
    char* p = wsb + off; off += bytes; return p;
  };

  // persistent
  u16* wcat4 = (u16*)alloc((size_t)4096*DD*2);   // [qw;kw;vw;sw_hi]
  u16* swcat = (u16*)alloc((size_t)DD*2048*2);   // [swlo | swhi]
  u16* owb   = (u16*)alloc((size_t)DD*DD*2);
  u16* fwcat = (u16*)alloc((size_t)2*DFF*DD*2);  // fw1/fw3 16-row interleave
  u16* fw2b  = (u16*)alloc((size_t)DD*DFF*2);
  u16* aupwb = (u16*)alloc((size_t)128*DD*2);
  u16* adnwb = (u16*)alloc((size_t)DD*128*2);
  u16* betwb = (u16*)alloc((size_t)128*DD*2);
  u16* u1wb  = (u16*)alloc((size_t)128*DD*2);
  u16* u2wb  = (u16*)alloc((size_t)DD*128*2);
  float* aupbp = (float*)alloc(128*4);
  float* betbp = (float*)alloc(128*4);
  float* u1bp  = (float*)alloc(128*4);
  u16* xbf  = (u16*)alloc((size_t)MM*DD*2);
  float* yatt  = (float*)alloc((size_t)MM*DD*4);
  u16* yattb = (u16*)alloc((size_t)MM*DD*2);
  float* invr  = (float*)alloc((size_t)MM*4);

  // early region
  size_t mark = off;
  u16* hcat = (u16*)alloc((size_t)MM*2048*2);    // [h_bf16 | h_lo]
  float* qkvd = (float*)alloc((size_t)MM*SKQ*4); // [q|k|v|drive]
  float* abase = (float*)alloc((size_t)MM*DD*4); // becomes alpha in place
  float* bbase = (float*)alloc((size_t)MM*128*4);
  float* bscale= (float*)alloc((size_t)MM*8*4);
  u64* spk = (u64*)alloc((size_t)BB*HH*TT*2*8);
  u16* gsm  = (u16*)alloc((size_t)MM*128*2);
  u16* g1e  = (u16*)alloc((size_t)MM*128*2);     // gate g1 (persists to fatB)
  float* gpre = (float*)alloc((size_t)MM*DD*4);  // gate pre (persists)
  // late region
  float* proj = (float*)alloc((size_t)MM*DD*4);
  u16* zbf  = (u16*)alloc((size_t)MM*DD*2);
  u16* ffh  = (u16*)alloc((size_t)MM*DFF*2);
  (void)mark;

  dim3 blk(256);

  // fatP: weight/input prep || row_rms
  prep_all<<<dim3(22145 + MM), blk, 0, stream>>>(
      qw, kw, vw, sw, ow, fw1, fw3, fw2, x, aupw, adnw, betw, u1w, u2w,
      aupb, betb, u1b,
      wcat4, swcat, owb, fwcat, fw2b, xbf, aupwb, adnwb, betwb, u1wb, u2wb,
      aupbp, betbp, u1bp, invr);

  conv_silu_k<<<dim3(MM), blk, 0, stream>>>(x, invr, nin, cw, cb, hcat);

  // fused q|k|v|drive_hi projection — 256^2 tile, ring-4 counted pipeline
  // K=DD (hi-half only; drive-lo fix comes from fatC) — R26's K=2048 was a bug
  gemm256<0><<<dim3(16,16), dim3(512), 0, stream>>>(hcat, wcat4, qkvd, nullptr,
                                                    DD, 2048, DD, SKQ);
  // fatC: drive-lo fix || beta base || qk_norm
  fatC<<<dim3(256 + 32 + MM*HH/4), blk, 0, stream>>>(hcat, swcat, qkvd,
                                                     betwb, bbase, betbp);
  // fatA: spike scan || alpha-up GEMM || gate-u1 GEMM
  fatA<<<dim3(96), blk, 0, stream>>>(qkvd+3072, bbase, bspk, mem0, spk, bscale,
                                     hcat, aupwb, gsm, aupbp,
                                     xbf, u1wb, g1e, u1bp);
  // alpha down-proj with fused spike+sigmoid epilogue
  gemm_bt<4><<<dim3(32,8), blk, 0, stream>>>(gsm, adnwb, abase, nullptr, adnb,
                                             spk, aspk, DD, 128, 128, 128, DD);

  // fatB: delta-rule scan || gate-u2 GEMM
  fatB<<<dim3(512), blk, 0, stream>>>(qkvd, abase, bscale, st0, yatt,
                                      g1e, u2wb, gpre, u2b);
  head_norm_k<<<dim3(MM*HH/4), blk, 0, stream>>>(yatt, hnw, yattb);

  // out proj, then combine(+rms+zscale fused)
  gemm_bt<0><<<dim3(32,8), blk, 0, stream>>>(yattb, owb, proj, nullptr, nullptr,
                                             nullptr, nullptr, DD, DD, DD, DD, DD);
  gate_rms_z<<<dim3(MM), blk, 0, stream>>>(x, proj, gpre, ffnw, out, zbf);

  // FFN: 256^2 swiglu GEMM (ring-4 pipeline), then down-proj accumulate
  gemm256<3><<<dim3(16,32), dim3(512), 0, stream>>>(zbf, fwcat, nullptr, ffh,
                                                    DD, DD, DD, DFF);
  gemm_bt<1><<<dim3(32,8), blk, 0, stream>>>(ffh, fw2b, out, nullptr, nullptr,
                                             nullptr, nullptr, DD, DFF, DFF, DFF, DD);
}